// Round 1
// 338.942 us; speedup vs baseline: 1.0151x; 1.0151x over previous
//
#include <hip/hip_runtime.h>
#include <hip/hip_bf16.h>
#include <math.h>

// ---------- types ----------
typedef __attribute__((ext_vector_type(8))) __bf16 bf16x8;
typedef __attribute__((ext_vector_type(4))) float f32x4;

// fp32 -> bf16 round-to-nearest-even
__device__ __forceinline__ unsigned short f2bf(float f) {
    union { float f; unsigned u; } v; v.f = f;
    unsigned r = v.u + 0x7fffu + ((v.u >> 16) & 1u);
    return (unsigned short)(r >> 16);
}
// pack two fp32 into one dword of two bf16 (lo, hi)
__device__ __forceinline__ unsigned int pk(float a, float b) {
    union { float f; unsigned u; } x, y; x.f = a; y.f = b;
    unsigned ra = (x.u + 0x7fffu + ((x.u >> 16) & 1u)) >> 16;
    unsigned rb = (y.u + 0x7fffu + ((y.u >> 16) & 1u)) & 0xffff0000u;
    return ra | rb;
}

// async global->LDS, 16 B per lane; LDS dest = wave-uniform base + lane*16
__device__ __forceinline__ void gl2lds16(const unsigned short* g, unsigned short* l) {
    __builtin_amdgcn_global_load_lds(
        (const __attribute__((address_space(1))) unsigned int*)(g),
        (__attribute__((address_space(3))) unsigned int*)(l), 16, 0, 0);
}

// ---------- setup kernel ----------
// block 0: packed membership table tbl[f] = used | (lslot+1)<<8
//          (not-fields get lslot=-1: their leftover slot is written by the
//           tanh GEMM epilogue directly, passthrough would be dead writes)
// blocks 1..448: weight transpose+convert, 64x64 LDS tiles
struct SetupArgs {
    const int *and_pairs, *or_pairs, *not_idx, *lidx;
    int* tbl;                       // 64 ints
    const float* W[5];
    unsigned short* WT[5];
    int K[5], N[5];
    int tstart[6];
};

__global__ __launch_bounds__(256) void setup_kernel(SetupArgs a) {
    __shared__ float tile[64][65];
    const int blk = blockIdx.x;
    const int tid = threadIdx.x;

    if (blk == 0) {
        if (tid < 64) {
            const int f = tid;
            int u = 0;
            for (int i = 0; i < 32; i++) u |= (a.and_pairs[i] == f);
            for (int i = 0; i < 16; i++) u |= (a.or_pairs[i] == f);
            int isnot = 0;
            for (int i = 0; i < 8; i++)  isnot |= (a.not_idx[i] == f);
            int ls = -1;
            for (int l = 0; l < 16; l++) if (a.lidx[l] == f) ls = l;
            if (isnot) ls = -1;          // tanh GEMM writes these slots
            a.tbl[f] = (u | isnot) | ((ls + 1) << 8);
        }
        return;
    }

    const int bx = blk - 1;
    int m = 0;
    while (bx >= a.tstart[m + 1]) m++;
    const float* src = a.W[m];
    unsigned short* dst = a.WT[m];
    const int K = a.K[m], N = a.N[m];
    const int t = bx - a.tstart[m];
    const int ntn = N >> 6;
    const int tk = t / ntn, tn = t % ntn;
    const int c = tid & 63, r0 = tid >> 6;
    #pragma unroll
    for (int r = r0; r < 64; r += 4)
        tile[r][c] = src[(size_t)(tk * 64 + r) * N + tn * 64 + c];
    __syncthreads();
    #pragma unroll
    for (int r = r0; r < 64; r += 4)
        dst[(size_t)(tn * 64 + r) * K + tk * 64 + c] = f2bf(tile[c][r]);
}

// ---------- prep kernel: pure streaming, no LDS, no syncs ----------
// fv fp32->bf16 for used fields + fp32 leftover passthrough to out.
// One wave spans exactly one field row (64 lanes x 8 floats = 512),
// so f and the table entry are wave-uniform -> broadcast load + uniform branches.
struct PrepArgs {
    const float* fv;
    unsigned short* fvb;
    const int* tbl;
    float* out;
};

__global__ __launch_bounds__(256) void prep_kernel(PrepArgs a) {
    const int t = blockIdx.x * 256 + threadIdx.x;   // 8 consecutive floats
    const size_t e = (size_t)t * 8;
    const int c = (int)(e & 511);
    const int f = (int)((e >> 9) & 63);
    const int b = (int)(e >> 15);
    // issue data loads and table load together (independent)
    const float4 v0 = *(const float4*)(a.fv + e);
    const float4 v1 = *(const float4*)(a.fv + e + 4);
    const int tb = a.tbl[f];                        // wave-uniform
    const int u  = tb & 0xff;
    const int ls = (tb >> 8) - 1;
    if (u) {
        uint4 o;
        o.x = pk(v0.x, v0.y); o.y = pk(v0.z, v0.w);
        o.z = pk(v1.x, v1.y); o.w = pk(v1.z, v1.w);
        ((uint4*)a.fvb)[t] = o;
    }
    if (ls >= 0) {
        float* d = a.out + ((size_t)b * 40 + 24 + ls) * 512 + c;
        *(float4*)(d)     = v0;
        *(float4*)(d + 4) = v1;
    }
}

// ---------- templated GEMM segment ----------
// C[M,512] = act(A[M,K] @ W[K,512] + bias); BM=BN=128, BK=32, 4 waves/block.
// 2-phase double-buffered K-loop: issue next tile's global_load_lds BEFORE
// the ds_read+MFMA of the current tile; single __syncthreads per K-step
// (its implicit vmcnt(0)+lgkmcnt(0) drain is the pipeline wait).
// LDS layout XOR-swizzled: 16B-chunk slot cp of row r holds k-chunk cp^(r&3);
// staged by permuting each lane's global source chunk (dest is base+lane*16);
// frag reads use chunk (lane>>4)^(lane&3)  ->  conflict-free (2-way max).
// SRCM: 0 = A row m = concat(fvb[b,idx[2p]], fvb[b,idx[2p+1]]), m=b*P+p, K=1024
//       1 = A row m = fvb[b, idx[i]], m=b*8+i
//       2 = plain bf16 A [M,K]
// EPIM: 0 = ReLU -> bf16 hid[m*512+n]
//       1 = +bias -> fp32 out[(b*40+QBASE+p)*512+n]
//       2 = tanh  -> fp32 out[(b*40+q)*512+n], q = 24+pos(idx[i] in leftover)
template <int P, int K, int SRCM, int EPIM, int QBASE>
__device__ __forceinline__ void gemm_seg(
    const unsigned short* __restrict__ A,
    const int* __restrict__ idx,
    const unsigned short* __restrict__ WT,
    const float* __restrict__ bias,
    unsigned short* __restrict__ hid_out,
    float* __restrict__ out,
    const int* __restrict__ leftover,
    int local,
    unsigned short* As, unsigned short* Bs) {

    const int tid  = threadIdx.x;
    const int lane = tid & 63, w = tid >> 6;
    const int tm = (local >> 2) * 128, tn = (local & 3) * 128;

    // staging: call c covers rows [w*32+c*16, +16); lane l -> row l>>2,
    // swizzled source k-chunk ((l&3)^((l>>2)&3))*8 shorts (16 B)
    const int lm  = lane >> 2;
    const int kin = (((lane & 3) ^ ((lane >> 2) & 3)) * 8);
    const unsigned short* ar0[2];
    const unsigned short* ar1[2];
    const unsigned short* wp[2];
    #pragma unroll
    for (int c = 0; c < 2; c++) {
        const int m = tm + w * 32 + c * 16 + lm;
        if constexpr (SRCM == 0) {
            const int b = m / P, p = m % P;
            ar0[c] = A + ((size_t)b * 64 + idx[2 * p]) * 512;
            ar1[c] = A + ((size_t)b * 64 + idx[2 * p + 1]) * 512;
        } else if constexpr (SRCM == 1) {
            const int b = m >> 3, i = m & 7;
            ar0[c] = A + ((size_t)b * 64 + idx[i]) * 512;
        } else {
            ar0[c] = A + (size_t)m * K;
        }
        const int n = tn + w * 32 + c * 16 + lm;
        wp[c] = WT + (size_t)n * K;
    }

    f32x4 acc[4][4];
    #pragma unroll
    for (int i = 0; i < 4; i++)
        #pragma unroll
        for (int j = 0; j < 4; j++)
            acc[i][j] = f32x4{0.f, 0.f, 0.f, 0.f};

    const int wm = (w & 1) * 64, wn = (w >> 1) * 64;
    const int xsel = ((lane >> 4) ^ (lane & 3)) * 8;   // lane-constant frag chunk

    auto stage = [&](int buf, int k0) {
        #pragma unroll
        for (int c = 0; c < 2; c++) {
            const unsigned short* asrc;
            if constexpr (SRCM == 0)
                asrc = (k0 >= 512 ? ar1[c] + (k0 - 512) : ar0[c] + k0) + kin;
            else
                asrc = ar0[c] + k0 + kin;
            gl2lds16(asrc, &As[buf * 4096 + w * 1024 + c * 512]);
            gl2lds16(wp[c] + k0 + kin, &Bs[buf * 4096 + w * 1024 + c * 512]);
        }
    };

    constexpr int NT = K / 32;
    stage(0, 0);
    __syncthreads();                           // buf0 staged (vmcnt drained)

    for (int t = 0; t < NT; t++) {
        const int cur = t & 1;
        if (t + 1 < NT) stage(cur ^ 1, (t + 1) * 32);   // prefetch next tile
        const unsigned short* Ab = &As[cur * 4096];
        const unsigned short* Bb = &Bs[cur * 4096];
        bf16x8 af[4], bfr[4];
        #pragma unroll
        for (int mi = 0; mi < 4; mi++)
            af[mi] = *(const bf16x8*)&Ab[(wm + mi * 16 + (lane & 15)) * 32 + xsel];
        #pragma unroll
        for (int ni = 0; ni < 4; ni++)
            bfr[ni] = *(const bf16x8*)&Bb[(wn + ni * 16 + (lane & 15)) * 32 + xsel];
        #pragma unroll
        for (int mi = 0; mi < 4; mi++)
            #pragma unroll
            for (int ni = 0; ni < 4; ni++)
                acc[mi][ni] = __builtin_amdgcn_mfma_f32_16x16x32_bf16(
                    af[mi], bfr[ni], acc[mi][ni], 0, 0, 0);
        __syncthreads();                        // drain prefetch, release LDS
    }

    // ---- epilogue ----
    const int col0 = tn + wn + (lane & 15);
    const int row0 = tm + wm + (lane >> 4) * 4;

    int qmap[8];
    if constexpr (EPIM == 2) {
        #pragma unroll
        for (int i = 0; i < 8; i++) {
            const int f = idx[i];
            int q = 24;
            for (int l = 0; l < 16; l++)
                if (leftover[l] == f) q = 24 + l;
            qmap[i] = q;
        }
    }

    #pragma unroll
    for (int ni = 0; ni < 4; ni++) {
        const int n  = col0 + ni * 16;
        const float bv = bias[n];
        #pragma unroll
        for (int mi = 0; mi < 4; mi++) {
            const int rbase = row0 + mi * 16;
            #pragma unroll
            for (int j = 0; j < 4; j++) {
                const int m = rbase + j;
                float v = acc[mi][ni][j] + bv;
                if constexpr (EPIM == 0) {
                    v = v > 0.f ? v : 0.f;
                    hid_out[(size_t)m * 512 + n] = f2bf(v);
                } else if constexpr (EPIM == 1) {
                    const int b = m / P, p = m % P;   // P constexpr -> shifts
                    out[((size_t)b * 40 + QBASE + p) * 512 + n] = v;
                } else {
                    const int b = m >> 3, i = m & 7;
                    out[((size_t)b * 40 + qmap[i]) * 512 + n] = tanhf(v);
                }
            }
        }
    }
}

// ---------- phase kernels ----------
struct L1Args {
    const unsigned short *fvb, *and_W1T, *or_W1T, *not_WT;
    const int *and_pairs, *or_pairs, *not_idx, *leftover;
    const float *and_b1, *or_b1, *not_b;
    unsigned short *and_hid, *or_hid;
    float* out;
};

__global__ __launch_bounds__(256, 3) void l1_phase(L1Args a) {
    __shared__ __align__(16) unsigned short As[2 * 128 * 32];
    __shared__ __align__(16) unsigned short Bs[2 * 128 * 32];
    const int blk = blockIdx.x;
    if (blk < 512)        // and-L1: M=16384, K=1024 -> hid
        gemm_seg<16, 1024, 0, 0, 0>(a.fvb, a.and_pairs, a.and_W1T, a.and_b1,
                                    a.and_hid, nullptr, nullptr, blk, As, Bs);
    else if (blk < 768)   // or-L1: M=8192, K=1024 -> hid
        gemm_seg<8, 1024, 0, 0, 0>(a.fvb, a.or_pairs, a.or_W1T, a.or_b1,
                                   a.or_hid, nullptr, nullptr, blk - 512, As, Bs);
    else                  // not: M=8192, K=512, tanh -> out
        gemm_seg<8, 512, 1, 2, 24>(a.fvb, a.not_idx, a.not_WT, a.not_b,
                                   nullptr, a.out, a.leftover, blk - 768, As, Bs);
}

struct L2Args {
    const unsigned short *and_hid, *or_hid, *and_W2T, *or_W2T;
    const float *and_b2, *or_b2;
    float* out;
};

__global__ __launch_bounds__(256, 3) void l2_phase(L2Args a) {
    __shared__ __align__(16) unsigned short As[2 * 128 * 32];
    __shared__ __align__(16) unsigned short Bs[2 * 128 * 32];
    const int blk = blockIdx.x;
    if (blk < 512)        // and-L2 -> out q=0..15
        gemm_seg<16, 512, 2, 1, 0>(a.and_hid, nullptr, a.and_W2T, a.and_b2,
                                   nullptr, a.out, nullptr, blk, As, Bs);
    else                  // or-L2 -> out q=16..23
        gemm_seg<8, 512, 2, 1, 16>(a.or_hid, nullptr, a.or_W2T, a.or_b2,
                                   nullptr, a.out, nullptr, blk - 512, As, Bs);
}

// ---------- launch ----------
extern "C" void kernel_launch(void* const* d_in, const int* in_sizes, int n_in,
                              void* d_out, int out_size, void* d_ws, size_t ws_size,
                              hipStream_t stream) {
    const float* fv       = (const float*)d_in[0];
    const float* and_W1   = (const float*)d_in[1];
    const float* and_b1   = (const float*)d_in[2];
    const float* and_W2   = (const float*)d_in[3];
    const float* and_b2   = (const float*)d_in[4];
    const float* or_W1    = (const float*)d_in[5];
    const float* or_b1    = (const float*)d_in[6];
    const float* or_W2    = (const float*)d_in[7];
    const float* or_b2    = (const float*)d_in[8];
    const float* not_W    = (const float*)d_in[9];
    const float* not_b    = (const float*)d_in[10];
    const int* not_idx    = (const int*)d_in[11];
    const int* and_pairs  = (const int*)d_in[12];
    const int* or_pairs   = (const int*)d_in[13];
    const int* leftover   = (const int*)d_in[14];
    float* out = (float*)d_out;
    char* ws = (char*)d_ws;

    // ws layout (bytes)
    unsigned short* fvb     = (unsigned short*)(ws);              // 64 MB bf16 fv
    unsigned short* and_W1T = (unsigned short*)(ws + 67108864);   // 1 MB
    unsigned short* or_W1T  = (unsigned short*)(ws + 68157440);   // 1 MB
    unsigned short* and_W2T = (unsigned short*)(ws + 69206016);   // 0.5 MB
    unsigned short* or_W2T  = (unsigned short*)(ws + 69730304);   // 0.5 MB
    unsigned short* not_WT  = (unsigned short*)(ws + 70254592);   // 0.5 MB
    unsigned short* and_hid = (unsigned short*)(ws + 70778880);   // 16 MB
    unsigned short* or_hid  = (unsigned short*)(ws + 87556096);   // 8 MB
    int*            tbl     = (int*)(ws + 95944704);              // 256 B

    SetupArgs sa;
    sa.and_pairs = and_pairs; sa.or_pairs = or_pairs;
    sa.not_idx = not_idx; sa.lidx = leftover; sa.tbl = tbl;
    sa.W[0] = and_W1; sa.WT[0] = and_W1T; sa.K[0] = 1024; sa.N[0] = 512;
    sa.W[1] = or_W1;  sa.WT[1] = or_W1T;  sa.K[1] = 1024; sa.N[1] = 512;
    sa.W[2] = and_W2; sa.WT[2] = and_W2T; sa.K[2] = 512;  sa.N[2] = 512;
    sa.W[3] = or_W2;  sa.WT[3] = or_W2T;  sa.K[3] = 512;  sa.N[3] = 512;
    sa.W[4] = not_W;  sa.WT[4] = not_WT;  sa.K[4] = 512;  sa.N[4] = 512;
    sa.tstart[0] = 0;   sa.tstart[1] = 128; sa.tstart[2] = 256;
    sa.tstart[3] = 320; sa.tstart[4] = 384; sa.tstart[5] = 448;
    setup_kernel<<<dim3(449), dim3(256), 0, stream>>>(sa);

    PrepArgs pa;
    pa.fv = fv; pa.fvb = fvb; pa.tbl = tbl; pa.out = out;
    prep_kernel<<<dim3(16384), dim3(256), 0, stream>>>(pa);

    L1Args g1;
    g1.fvb = fvb; g1.and_W1T = and_W1T; g1.or_W1T = or_W1T; g1.not_WT = not_WT;
    g1.and_pairs = and_pairs; g1.or_pairs = or_pairs; g1.not_idx = not_idx;
    g1.leftover = leftover;
    g1.and_b1 = and_b1; g1.or_b1 = or_b1; g1.not_b = not_b;
    g1.and_hid = and_hid; g1.or_hid = or_hid; g1.out = out;
    l1_phase<<<dim3(1024), dim3(256), 0, stream>>>(g1);

    L2Args g2;
    g2.and_hid = and_hid; g2.or_hid = or_hid;
    g2.and_W2T = and_W2T; g2.or_W2T = or_W2T;
    g2.and_b2 = and_b2; g2.or_b2 = or_b2; g2.out = out;
    l2_phase<<<dim3(768), dim3(256), 0, stream>>>(g2);
}